// Round 4
// baseline (254.485 us; speedup 1.0000x reference)
//
#include <hip/hip_runtime.h>

#define WS   7
#define NH   8
#define HD   32          // head dim
#define WIN  49          // WS*WS
#define HALO 9           // WS + 2
#define VHST 34          // halo pixel stride in HALFS: bank=(17p+d2)%32, 17 odd -> ~2-way max
#define UPB  4           // (window,head) units per block = waves per block

typedef __fp16 h2 __attribute__((ext_vector_type(2)));
typedef __fp16 h4 __attribute__((ext_vector_type(4)));
typedef __fp16 h8 __attribute__((ext_vector_type(8)));

__global__ __launch_bounds__(64 * UPB, 4)
void win_attn_lepe(const float* __restrict__ qkv,
                   const float* __restrict__ lw,
                   const float* __restrict__ lb,
                   float* __restrict__ out,
                   int B, int H, int W, int C)
{
    const int N  = H * W;
    const int Gw = W / WS;
    const int Gh = H / WS;
    const int G  = Gh * Gw;

    const int wave = threadIdx.x >> 6;
    const int lane = threadIdx.x & 63;

    // unit = (window id)*NH + head; 4 consecutive units per block -> same window, 4 heads
    const int unit = blockIdx.x * UPB + wave;
    const int wid  = unit >> 3;               // NH == 8
    const int h    = unit & 7;
    const int b    = wid / G;
    const int g    = wid % G;
    const int gy   = g / Gw, gx = g % Gw;
    const int row0 = gy * WS, col0 = gx * WS;
    const int c0   = h * HD;

    const size_t plane = (size_t)B * N * C;
    const float* q_base = qkv + (size_t)b * N * C;
    const float* k_base = q_base + plane;
    const float* v_base = q_base + 2 * plane;

    __shared__ __fp16 sK [UPB][WIN * HD];            // [49][32] K window, b128 uniform reads
    __shared__ __fp16 sVw[UPB][WIN * HD];            // [49][32] window V for PV
    __shared__ __fp16 sVh[UPB][HALO * HALO * VHST];  // [81][34] halo V for lepe
    __shared__ __fp16 sW [UPB][9 * HD];              // [tap][32] lepe weights
    __shared__ float  sB [UPB][HD];

    // ---- stage K window as f16 ----
    for (int idx = lane; idx < WIN * 8; idx += 64) {
        int n  = idx >> 3;
        int d4 = (idx & 7) * 4;
        int r = row0 + n / WS, c = col0 + n % WS;
        float4 f = *reinterpret_cast<const float4*>(k_base + ((size_t)r * W + c) * C + c0 + d4);
        h2 a  = __builtin_amdgcn_cvt_pkrtz(f.x, f.y);
        h2 bb = __builtin_amdgcn_cvt_pkrtz(f.z, f.w);
        h4 v4 = { a.x, a.y, bb.x, bb.y };
        *reinterpret_cast<h4*>(&sK[wave][n * HD + d4]) = v4;
    }

    // ---- stage V halo (f16) + duplicate window region into sVw ----
    for (int idx = lane; idx < HALO * HALO * 8; idx += 64) {
        int p  = idx >> 3;
        int d4 = (idx & 7) * 4;
        int py = p / HALO, px = p % HALO;
        int ry = row0 - 1 + py, rx = col0 - 1 + px;
        bool in = (ry >= 0 && ry < H && rx >= 0 && rx < W);
        float4 f = make_float4(0.f, 0.f, 0.f, 0.f);
        if (in) f = *reinterpret_cast<const float4*>(v_base + ((size_t)ry * W + rx) * C + c0 + d4);
        h2 a  = __builtin_amdgcn_cvt_pkrtz(f.x, f.y);
        h2 bb = __builtin_amdgcn_cvt_pkrtz(f.z, f.w);
        *reinterpret_cast<h2*>(&sVh[wave][p * VHST + d4])     = a;
        *reinterpret_cast<h2*>(&sVh[wave][p * VHST + d4 + 2]) = bb;
        if (py >= 1 && py <= WS && px >= 1 && px <= WS) {
            int m = (py - 1) * WS + (px - 1);
            h4 v4 = { a.x, a.y, bb.x, bb.y };
            *reinterpret_cast<h4*>(&sVw[wave][m * HD + d4]) = v4;
        }
    }

    // ---- stage lepe weights (tap-major) + bias ----
    for (int i = lane; i < HD * 9; i += 64) {
        int d = i / 9, t = i % 9;
        sW[wave][t * HD + d] = (__fp16)lw[(size_t)(c0 + d) * 9 + t];
    }
    if (lane < HD) sB[wave][lane] = lb[c0 + lane];

    __syncthreads();

    if (lane < WIN) {
        const int wy = lane / WS, wx = lane % WS;
        const int r = row0 + wy, c = col0 + wx;

        // q -> f16 pairs in registers, pre-scaled
        const float scale = 0.17677669529663687f;   // 32^-0.5
        h2 qh[16];
        const float* qp = q_base + ((size_t)r * W + c) * C + c0;
        #pragma unroll
        for (int d4 = 0; d4 < 8; ++d4) {
            float4 f = *reinterpret_cast<const float4*>(qp + d4 * 4);
            qh[2 * d4]     = __builtin_amdgcn_cvt_pkrtz(f.x * scale, f.y * scale);
            qh[2 * d4 + 1] = __builtin_amdgcn_cvt_pkrtz(f.z * scale, f.w * scale);
        }

        // scores via v_dot2_f32_f16 (fp32 accumulate); sK reads wave-uniform broadcast
        float s[WIN];
        #pragma unroll
        for (int m = 0; m < WIN; ++m) {
            const h8* kr = reinterpret_cast<const h8*>(&sK[wave][m * HD]);
            float acc = 0.f;
            #pragma unroll
            for (int j = 0; j < 4; ++j) {
                h8 kv = kr[j];
                h2 k0 = { kv[0], kv[1] }, k1 = { kv[2], kv[3] };
                h2 k2 = { kv[4], kv[5] }, k3 = { kv[6], kv[7] };
                acc = __builtin_amdgcn_fdot2(qh[4 * j + 0], k0, acc, false);
                acc = __builtin_amdgcn_fdot2(qh[4 * j + 1], k1, acc, false);
                acc = __builtin_amdgcn_fdot2(qh[4 * j + 2], k2, acc, false);
                acc = __builtin_amdgcn_fdot2(qh[4 * j + 3], k3, acc, false);
            }
            s[m] = acc;
        }

        // softmax (lane-local, fp32)
        float mx = s[0];
        #pragma unroll
        for (int m = 1; m < WIN; ++m) mx = fmaxf(mx, s[m]);
        float sum = 0.f;
        #pragma unroll
        for (int m = 0; m < WIN; ++m) { s[m] = __expf(s[m] - mx); sum += s[m]; }
        const float inv = 1.f / sum;

        // out = P @ V, fp32 accumulate (v_fma_mix)
        float o[HD];
        #pragma unroll
        for (int d = 0; d < HD; ++d) o[d] = 0.f;
        #pragma unroll
        for (int m = 0; m < WIN; ++m) {
            float pf = s[m] * inv;
            const h8* vr = reinterpret_cast<const h8*>(&sVw[wave][m * HD]);
            #pragma unroll
            for (int j = 0; j < 4; ++j) {
                h8 vv = vr[j];
                #pragma unroll
                for (int e = 0; e < 8; ++e)
                    o[j * 8 + e] += pf * (float)vv[e];
            }
        }

        // lepe: depthwise 3x3 + bias, fp32 accumulate
        #pragma unroll
        for (int t = 0; t < 9; ++t) {
            int dh = t / 3, dw = t % 3;
            const __fp16* vb = &sVh[wave][((wy + dh) * HALO + (wx + dw)) * VHST];
            const __fp16* wb = &sW[wave][t * HD];
            #pragma unroll
            for (int d2 = 0; d2 < 16; ++d2) {
                h2 w2 = *reinterpret_cast<const h2*>(&wb[2 * d2]);   // uniform
                h2 v2 = *reinterpret_cast<const h2*>(&vb[2 * d2]);   // ~2-way banks
                o[2 * d2]     += (float)w2.x * (float)v2.x;
                o[2 * d2 + 1] += (float)w2.y * (float)v2.y;
            }
        }

        // write out[b, r*W+c, c0..c0+31]
        float* dst = out + ((size_t)b * N + (size_t)r * W + c) * C + c0;
        #pragma unroll
        for (int d4 = 0; d4 < 8; ++d4) {
            float4 t4 = make_float4(o[4 * d4]     + sB[wave][4 * d4],
                                    o[4 * d4 + 1] + sB[wave][4 * d4 + 1],
                                    o[4 * d4 + 2] + sB[wave][4 * d4 + 2],
                                    o[4 * d4 + 3] + sB[wave][4 * d4 + 3]);
            *reinterpret_cast<float4*>(dst + d4 * 4) = t4;
        }
    }
}

extern "C" void kernel_launch(void* const* d_in, const int* in_sizes, int n_in,
                              void* d_out, int out_size, void* d_ws, size_t ws_size,
                              hipStream_t stream) {
    const float* qkv = (const float*)d_in[0];
    const float* lw  = (const float*)d_in[1];
    const float* lb  = (const float*)d_in[2];
    float* out = (float*)d_out;

    const int H = 112, W = 112;
    const int C = in_sizes[2];                 // lepe_b has C elements
    const int N = H * W;
    const int B = in_sizes[0] / (3 * N * C);
    const int Gh = H / WS, Gw = W / WS;

    const int units = B * Gh * Gw * NH;        // 16384 for the bench shape; divisible by UPB
    win_attn_lepe<<<units / UPB, 64 * UPB, 0, stream>>>(qkv, lw, lb, out, B, H, W, C);
}

// Round 5
// 151.127 us; speedup vs baseline: 1.6839x; 1.6839x over previous
//
#include <hip/hip_runtime.h>

#define WS   7
#define NH   8
#define HD   32
#define WIN  49
#define HALO 9
#define VHST 44      // sVh stride in halfs (8B-aligned rows, spread banks)
#define PST  76      // sP stride in halfs (8B-aligned rows, spread banks)

typedef __fp16 h2  __attribute__((ext_vector_type(2)));
typedef __fp16 v4h __attribute__((ext_vector_type(4)));
typedef float  v4f __attribute__((ext_vector_type(4)));

__global__ __launch_bounds__(64)
void win_attn_lepe(const float* __restrict__ qkv,
                   const float* __restrict__ lw,
                   const float* __restrict__ lb,
                   float* __restrict__ out,
                   int B, int H, int W, int C)
{
    const int N  = H * W;
    const int Gw = W / WS;
    const int G  = (H / WS) * Gw;

    const int unit = blockIdx.x;          // (window)*NH + head
    const int wid  = unit >> 3;
    const int h    = unit & 7;
    const int b    = wid / G;
    const int g    = wid % G;
    const int gy   = g / Gw, gx = g % Gw;
    const int row0 = gy * WS, col0 = gx * WS;
    const int c0   = h * HD;

    const size_t plane = (size_t)B * N * C;
    const float* qb = qkv + (size_t)b * N * C;
    const float* kb = qb + plane;
    const float* vb = qb + 2 * plane;

    const int l  = threadIdx.x;
    const int lr = l & 15;     // row (A) / col (B,C) within 16
    const int gq = l >> 4;     // k-group

    __shared__ __fp16 sVh[HALO * HALO * VHST];  // V halo f16, [81][44]
    __shared__ __fp16 sW [9 * HD];              // lepe weights [tap][32]
    __shared__ __fp16 sP [16 * PST];            // P bounce for one M-tile [16][76]

    // ---- stage V halo (f16, zero-padded at image boundary) ----
    for (int idx = l; idx < HALO * HALO * 8; idx += 64) {
        int p  = idx >> 3;
        int d4 = (idx & 7) * 4;
        int ry = row0 - 1 + p / HALO, rx = col0 - 1 + p % HALO;
        bool in = (ry >= 0 && ry < H && rx >= 0 && rx < W);
        float4 f = make_float4(0.f, 0.f, 0.f, 0.f);
        if (in) f = *reinterpret_cast<const float4*>(vb + ((size_t)ry * W + rx) * C + c0 + d4);
        h2 a  = __builtin_amdgcn_cvt_pkrtz(f.x, f.y);
        h2 b2 = __builtin_amdgcn_cvt_pkrtz(f.z, f.w);
        v4h v4 = { a.x, a.y, b2.x, b2.y };
        *reinterpret_cast<v4h*>(&sVh[p * VHST + d4]) = v4;
    }
    // ---- stage lepe weights: sW[tap*32+d] = lw[(c0+d)*9+tap] ----
    for (int i = l; i < 288; i += 64) {
        int d = i & 31, t = i >> 5;
        sW[t * 32 + d] = (__fp16)lw[(size_t)(c0 + d) * 9 + t];
    }
    __syncthreads();

    // pixel p (0..63, clamped to 48) -> global offset of its channel block
    auto pixoff = [&](int p) -> size_t {
        p = p > 48 ? 48 : p;
        int r = row0 + p / WS, c = col0 + p % WS;
        return ((size_t)r * W + c) * C + c0;
    };

    const float scale = 0.17677669529663687f;   // 32^-0.5

    // ---- operand fragments, loaded straight from global in fragment order ----
    // Q A-frag [m][s]: Q[16m+lr][16s+4gq+j]  (scale folded)
    v4h qf[4][2];
    #pragma unroll
    for (int m = 0; m < 4; ++m) {
        size_t off = pixoff(16 * m + lr);
        #pragma unroll
        for (int s = 0; s < 2; ++s) {
            float4 f = *reinterpret_cast<const float4*>(qb + off + 16 * s + 4 * gq);
            h2 a  = __builtin_amdgcn_cvt_pkrtz(f.x * scale, f.y * scale);
            h2 b2 = __builtin_amdgcn_cvt_pkrtz(f.z * scale, f.w * scale);
            qf[m][s] = v4h{ a.x, a.y, b2.x, b2.y };
        }
    }
    // K B-frag [t][s]: K[16t+lr][16s+4gq+j]   (B col = key = lr)
    v4h kf[4][2];
    #pragma unroll
    for (int t = 0; t < 4; ++t) {
        size_t off = pixoff(16 * t + lr);
        #pragma unroll
        for (int s = 0; s < 2; ++s) {
            float4 f = *reinterpret_cast<const float4*>(kb + off + 16 * s + 4 * gq);
            h2 a  = __builtin_amdgcn_cvt_pkrtz(f.x, f.y);
            h2 b2 = __builtin_amdgcn_cvt_pkrtz(f.z, f.w);
            kf[t][s] = v4h{ a.x, a.y, b2.x, b2.y };
        }
    }
    // V B-frag [s4][n]: V[16*s4+4gq+j][16n+lr]
    v4h vf[4][2];
    #pragma unroll
    for (int s4 = 0; s4 < 4; ++s4) {
        #pragma unroll
        for (int n = 0; n < 2; ++n) {
            float e0 = vb[pixoff(16 * s4 + 4 * gq + 0) + 16 * n + lr];
            float e1 = vb[pixoff(16 * s4 + 4 * gq + 1) + 16 * n + lr];
            float e2 = vb[pixoff(16 * s4 + 4 * gq + 2) + 16 * n + lr];
            float e3 = vb[pixoff(16 * s4 + 4 * gq + 3) + 16 * n + lr];
            h2 a  = __builtin_amdgcn_cvt_pkrtz(e0, e1);
            h2 b2 = __builtin_amdgcn_cvt_pkrtz(e2, e3);
            vf[s4][n] = v4h{ a.x, a.y, b2.x, b2.y };
        }
    }
    // lepe weight / bias fragments: ch = 16n + lr
    float wf[9][2];
    #pragma unroll
    for (int t = 0; t < 9; ++t) {
        wf[t][0] = (float)sW[t * 32 + lr];
        wf[t][1] = (float)sW[t * 32 + 16 + lr];
    }
    float bias[2] = { lb[c0 + lr], lb[c0 + 16 + lr] };

    // ---- per M-tile: QK^T -> softmax -> P bounce -> PV -> lepe -> store ----
    #pragma unroll 1
    for (int m = 0; m < 4; ++m) {
        v4f sa[4] = { v4f{0,0,0,0}, v4f{0,0,0,0}, v4f{0,0,0,0}, v4f{0,0,0,0} };
        #pragma unroll
        for (int t = 0; t < 4; ++t)
            #pragma unroll
            for (int s = 0; s < 2; ++s)
                sa[t] = __builtin_amdgcn_mfma_f32_16x16x16f16(qf[m][s], kf[t][s], sa[t], 0, 0, 0);

        // mask padded keys (col = 16t + lr)
        #pragma unroll
        for (int t = 0; t < 4; ++t)
            if (16 * t + lr >= WIN) { sa[t][0] = -1e30f; sa[t][1] = -1e30f; sa[t][2] = -1e30f; sa[t][3] = -1e30f; }

        // row softmax: row r lives across the 16 lanes sharing gq
        float inv[4];
        #pragma unroll
        for (int r = 0; r < 4; ++r) {
            float mx = fmaxf(fmaxf(sa[0][r], sa[1][r]), fmaxf(sa[2][r], sa[3][r]));
            mx = fmaxf(mx, __shfl_xor(mx, 1));
            mx = fmaxf(mx, __shfl_xor(mx, 2));
            mx = fmaxf(mx, __shfl_xor(mx, 4));
            mx = fmaxf(mx, __shfl_xor(mx, 8));
            float e0 = __expf(sa[0][r] - mx), e1 = __expf(sa[1][r] - mx);
            float e2 = __expf(sa[2][r] - mx), e3 = __expf(sa[3][r] - mx);
            sa[0][r] = e0; sa[1][r] = e1; sa[2][r] = e2; sa[3][r] = e3;
            float sm = e0 + e1 + e2 + e3;
            sm += __shfl_xor(sm, 1);
            sm += __shfl_xor(sm, 2);
            sm += __shfl_xor(sm, 4);
            sm += __shfl_xor(sm, 8);
            inv[r] = 1.f / sm;
        }

        // write P (normalized, f16) to sP[query_in_tile][key]
        #pragma unroll
        for (int r = 0; r < 4; ++r) {
            int q = 4 * gq + r;
            #pragma unroll
            for (int t = 0; t < 4; ++t)
                sP[q * PST + 16 * t + lr] = (__fp16)(sa[t][r] * inv[r]);
        }
        __syncthreads();

        // PV: A = P rows (lr), k = 16*s4 + 4gq + j ; B = V frags
        v4f oa[2] = { v4f{0,0,0,0}, v4f{0,0,0,0} };
        #pragma unroll
        for (int s4 = 0; s4 < 4; ++s4) {
            v4h pa = *reinterpret_cast<const v4h*>(&sP[lr * PST + 16 * s4 + 4 * gq]);
            oa[0] = __builtin_amdgcn_mfma_f32_16x16x16f16(pa, vf[s4][0], oa[0], 0, 0, 0);
            oa[1] = __builtin_amdgcn_mfma_f32_16x16x16f16(pa, vf[s4][1], oa[1], 0, 0, 0);
        }
        __syncthreads();   // protect sP before next M-tile overwrites

        // lepe (fragment layout) + store: pixel p = 16m + 4gq + r, ch = 16n + lr
        #pragma unroll
        for (int r = 0; r < 4; ++r) {
            int p  = 16 * m + 4 * gq + r;
            int pc = p > 48 ? 48 : p;
            int wy = pc / WS, wx = pc % WS;
            #pragma unroll
            for (int n = 0; n < 2; ++n) {
                float acc = bias[n];
                #pragma unroll
                for (int dh = 0; dh < 3; ++dh)
                    #pragma unroll
                    for (int dw = 0; dw < 3; ++dw)
                        acc += wf[dh * 3 + dw][n] *
                               (float)sVh[((wy + dh) * HALO + (wx + dw)) * VHST + 16 * n + lr];
                if (p < WIN) {
                    int rr = row0 + p / WS, cc = col0 + p % WS;
                    out[((size_t)b * N + (size_t)rr * W + cc) * C + c0 + 16 * n + lr] = oa[n][r] + acc;
                }
            }
        }
    }
}

extern "C" void kernel_launch(void* const* d_in, const int* in_sizes, int n_in,
                              void* d_out, int out_size, void* d_ws, size_t ws_size,
                              hipStream_t stream) {
    const float* qkv = (const float*)d_in[0];
    const float* lw  = (const float*)d_in[1];
    const float* lb  = (const float*)d_in[2];
    float* out = (float*)d_out;

    const int H = 112, W = 112;
    const int C = in_sizes[2];
    const int N = H * W;
    const int B = in_sizes[0] / (3 * N * C);
    const int G = (H / WS) * (W / WS);

    const int units = B * G * NH;   // 16384
    win_attn_lepe<<<units, 64, 0, stream>>>(qkv, lw, lb, out, B, H, W, C);
}

// Round 7
// 148.031 us; speedup vs baseline: 1.7191x; 1.0209x over previous
//
#include <hip/hip_runtime.h>

#define WS   7
#define NH   8
#define HD   32
#define WIN  49
#define HALO 9
#define VHST 36      // sVh row stride in halfs (72B rows, 8B aligned)
#define PST  72      // sP row stride in halfs (>=64 keys + pad; 144B rows, 8B-aligned v4h reads)
#define LST  34      // sLepe row stride in halfs (68B rows, h2-aligned)

typedef __fp16 h2  __attribute__((ext_vector_type(2)));
typedef __fp16 v4h __attribute__((ext_vector_type(4)));
typedef float  v4f __attribute__((ext_vector_type(4)));

__global__ __launch_bounds__(64)
void win_attn_lepe(const float* __restrict__ qkv,
                   const float* __restrict__ lw,
                   const float* __restrict__ lb,
                   float* __restrict__ out,
                   int B, int H, int W, int C)
{
    const int N  = H * W;
    const int Gw = W / WS;
    const int G  = (H / WS) * Gw;

    const int unit = blockIdx.x;          // (window)*NH + head
    const int wid  = unit >> 3;
    const int h    = unit & 7;
    const int b    = wid / G;
    const int g    = wid % G;
    const int gy   = g / Gw, gx = g % Gw;
    const int row0 = gy * WS, col0 = gx * WS;
    const int c0   = h * HD;

    const size_t plane = (size_t)B * N * C;
    const float* qb = qkv + (size_t)b * N * C;
    const float* kb = qb + plane;
    const float* vb = qb + 2 * plane;

    const int l  = threadIdx.x;
    const int lr = l & 15;     // A-row / B-col / C-col index
    const int gq = l >> 4;     // k-group

    __shared__ __fp16 sVh  [HALO * HALO * VHST]; // V halo f16 [81][36]
    __shared__ __fp16 sW2  [16 * 20];            // lepe w as h2: [cp][2t+e]
    __shared__ __fp16 sLepe[WIN * LST];          // lepe result f16 [49][34]
    __shared__ __fp16 sP   [16 * PST];           // P bounce [16][72] (64 keys + pad)

    // ---- stage V halo (f16, zero-padded at image boundary) ----
    for (int idx = l; idx < HALO * HALO * 8; idx += 64) {
        int p  = idx >> 3;
        int d4 = (idx & 7) * 4;
        int ry = row0 - 1 + p / HALO, rx = col0 - 1 + p % HALO;
        bool in = (ry >= 0 && ry < H && rx >= 0 && rx < W);
        float4 f = make_float4(0.f, 0.f, 0.f, 0.f);
        if (in) f = *reinterpret_cast<const float4*>(vb + ((size_t)ry * W + rx) * C + c0 + d4);
        h2 a  = __builtin_amdgcn_cvt_pkrtz(f.x, f.y);
        h2 b2 = __builtin_amdgcn_cvt_pkrtz(f.z, f.w);
        v4h v4 = { a.x, a.y, b2.x, b2.y };
        *reinterpret_cast<v4h*>(&sVh[p * VHST + d4]) = v4;
    }
    // ---- stage lepe weights as h2-pairs: sW2[cp*20+2t+e] = lw[(c0+2cp+e)*9+t] ----
    for (int i = l; i < 288; i += 64) {
        int d = i / 9, t = i - d * 9;
        sW2[(d >> 1) * 20 + 2 * t + (d & 1)] = (__fp16)lw[(size_t)(c0 + d) * 9 + t];
    }
    __syncthreads();

    const float bias0 = lb[c0 + lr];
    const float bias1 = lb[c0 + 16 + lr];

    // pixel p (clamped to 48) -> global offset of its channel block
    auto pixoff = [&](int p) -> size_t {
        p = p > 48 ? 48 : p;
        int r = row0 + p / WS, c = col0 + p % WS;
        return ((size_t)r * W + c) * C + c0;
    };

    const float scale = 0.17677669529663687f;   // 32^-0.5

    // ---- Q A-frags [m][s]: Q[16m+lr][16s+4gq+j], scale folded ----
    v4h qf[4][2];
    #pragma unroll
    for (int m = 0; m < 4; ++m) {
        size_t off = pixoff(16 * m + lr);
        #pragma unroll
        for (int s = 0; s < 2; ++s) {
            float4 f = *reinterpret_cast<const float4*>(qb + off + 16 * s + 4 * gq);
            h2 a  = __builtin_amdgcn_cvt_pkrtz(f.x * scale, f.y * scale);
            h2 b2 = __builtin_amdgcn_cvt_pkrtz(f.z * scale, f.w * scale);
            qf[m][s] = v4h{ a.x, a.y, b2.x, b2.y };
        }
    }
    // ---- K B-frags [t][s]: K[16t+lr][16s+4gq+j] ----
    v4h kf[4][2];
    #pragma unroll
    for (int t = 0; t < 4; ++t) {
        size_t off = pixoff(16 * t + lr);
        #pragma unroll
        for (int s = 0; s < 2; ++s) {
            float4 f = *reinterpret_cast<const float4*>(kb + off + 16 * s + 4 * gq);
            h2 a  = __builtin_amdgcn_cvt_pkrtz(f.x, f.y);
            h2 b2 = __builtin_amdgcn_cvt_pkrtz(f.z, f.w);
            kf[t][s] = v4h{ a.x, a.y, b2.x, b2.y };
        }
    }

    // ---- V B-frags [s4][n]: V[16s4+4gq+j][16n+lr], read from sVh (f16) ----
    v4h vf[4][2];
    #pragma unroll
    for (int s4 = 0; s4 < 4; ++s4) {
        #pragma unroll
        for (int j = 0; j < 4; ++j) {
            int p  = 16 * s4 + 4 * gq + j;
            int pc = p > 48 ? 48 : p;
            int hp = (pc / WS + 1) * HALO + pc % WS + 1;
            int base = hp * VHST + lr;
            vf[s4][0][j] = sVh[base];
            vf[s4][1][j] = sVh[base + 16];
        }
    }

    // ---- cooperative LePE: sLepe[pix][ch] via packed f16 fma ----
    {
        h2 w2r[9];
        #pragma unroll
        for (int t = 0; t < 9; ++t)
            w2r[t] = *reinterpret_cast<const h2*>(&sW2[lr * 20 + 2 * t]);
        #pragma unroll 1
        for (int it = 0; it < 13; ++it) {
            int pix = it * 4 + gq;               // cp = lr
            if (pix < WIN) {
                int wy = pix / WS, wx = pix - (pix / WS) * WS;
                h2 acc = h2{ (__fp16)0.f, (__fp16)0.f };
                #pragma unroll
                for (int dh = 0; dh < 3; ++dh)
                    #pragma unroll
                    for (int dw = 0; dw < 3; ++dw) {
                        h2 v = *reinterpret_cast<const h2*>(
                            &sVh[((wy + dh) * HALO + (wx + dw)) * VHST + 2 * lr]);
                        acc += w2r[dh * 3 + dw] * v;
                    }
                *reinterpret_cast<h2*>(&sLepe[pix * LST + 2 * lr]) = acc;
            }
        }
    }
    __syncthreads();

    const v4h ones = { (__fp16)1.f, (__fp16)1.f, (__fp16)1.f, (__fp16)1.f };

    // ---- per M-tile: QK^T -> exp(s-3) (no max, no shfl) -> P bounce -> PV(+den) -> store ----
    #pragma unroll 1
    for (int m = 0; m < 4; ++m) {
        v4f sa[4] = { v4f{0,0,0,0}, v4f{0,0,0,0}, v4f{0,0,0,0}, v4f{0,0,0,0} };
        #pragma unroll
        for (int t = 0; t < 4; ++t)
            #pragma unroll
            for (int s = 0; s < 2; ++s)
                sa[t] = __builtin_amdgcn_mfma_f32_16x16x16f16(qf[m][s], kf[t][s], sa[t], 0, 0, 0);

        // P~ = exp(score - 3) (unnormalized, shift-invariant), padded keys -> 0
        #pragma unroll
        for (int t = 0; t < 4; ++t) {
            bool valid = (16 * t + lr) < WIN;
            #pragma unroll
            for (int r = 0; r < 4; ++r) {
                float e = valid ? __expf(sa[t][r] - 3.f) : 0.f;
                sP[(4 * gq + r) * PST + 16 * t + lr] = (__fp16)e;
            }
        }
        __syncthreads();

        // PV + denominator on the matrix pipe
        v4f oa0 = v4f{0,0,0,0}, oa1 = v4f{0,0,0,0}, od = v4f{0,0,0,0};
        #pragma unroll
        for (int s4 = 0; s4 < 4; ++s4) {
            v4h pa = *reinterpret_cast<const v4h*>(&sP[lr * PST + 16 * s4 + 4 * gq]);
            oa0 = __builtin_amdgcn_mfma_f32_16x16x16f16(pa, vf[s4][0], oa0, 0, 0, 0);
            oa1 = __builtin_amdgcn_mfma_f32_16x16x16f16(pa, vf[s4][1], oa1, 0, 0, 0);
            od  = __builtin_amdgcn_mfma_f32_16x16x16f16(pa, ones,      od,  0, 0, 0);
        }
        __syncthreads();   // protect sP before next M-tile

        // epilogue: normalize, + lepe + bias, store
        #pragma unroll
        for (int r = 0; r < 4; ++r) {
            int p = 16 * m + 4 * gq + r;
            if (p < WIN) {
                float inv = __builtin_amdgcn_rcpf(od[r]);
                int rr = row0 + p / WS, cc = col0 + p % WS;
                float* dst = out + ((size_t)b * N + (size_t)rr * W + cc) * C + c0 + lr;
                dst[0]  = oa0[r] * inv + (float)sLepe[p * LST + lr]      + bias0;
                dst[16] = oa1[r] * inv + (float)sLepe[p * LST + 16 + lr] + bias1;
            }
        }
    }
}

extern "C" void kernel_launch(void* const* d_in, const int* in_sizes, int n_in,
                              void* d_out, int out_size, void* d_ws, size_t ws_size,
                              hipStream_t stream) {
    const float* qkv = (const float*)d_in[0];
    const float* lw  = (const float*)d_in[1];
    const float* lb  = (const float*)d_in[2];
    float* out = (float*)d_out;

    const int H = 112, W = 112;
    const int C = in_sizes[2];
    const int N = H * W;
    const int B = in_sizes[0] / (3 * N * C);
    const int G = (H / WS) * (W / WS);

    const int units = B * G * NH;   // 16384
    win_attn_lepe<<<units, 64, 0, stream>>>(qkv, lw, lb, out, B, H, W, C);
}

// Round 8
// 145.826 us; speedup vs baseline: 1.7451x; 1.0151x over previous
//
#include <hip/hip_runtime.h>

#define WS   7
#define NH   8
#define HD   32
#define WIN  49
#define HALO 9
#define VHST 36      // sVh row stride in halfs (72B rows, 8B aligned)
#define LST  34      // sLepe row stride in halfs (68B rows, h2-aligned)

typedef __fp16 h2  __attribute__((ext_vector_type(2)));
typedef __fp16 v4h __attribute__((ext_vector_type(4)));
typedef float  v4f __attribute__((ext_vector_type(4)));

__global__ __launch_bounds__(64)
void win_attn_lepe(const float* __restrict__ qkv,
                   const float* __restrict__ lw,
                   const float* __restrict__ lb,
                   float* __restrict__ out,
                   int B, int H, int W, int C)
{
    const int N  = H * W;
    const int Gw = W / WS;
    const int G  = (H / WS) * Gw;

    const int unit = blockIdx.x;          // (window)*NH + head
    const int wid  = unit >> 3;
    const int h    = unit & 7;
    const int b    = wid / G;
    const int g    = wid % G;
    const int gy   = g / Gw, gx = g % Gw;
    const int row0 = gy * WS, col0 = gx * WS;
    const int c0   = h * HD;

    const size_t plane = (size_t)B * N * C;
    const float* qb = qkv + (size_t)b * N * C;
    const float* kb = qb + plane;
    const float* vb = qb + 2 * plane;

    const int l  = threadIdx.x;
    const int lr = l & 15;     // A-row / B-col / C-col index
    const int gq = l >> 4;     // k-group

    __shared__ __fp16 sVh  [HALO * HALO * VHST]; // V halo f16 [81][36]
    __shared__ __fp16 sW2  [16 * 20];            // lepe w as h2: [cp][2t+e]
    __shared__ __fp16 sLepe[WIN * LST];          // lepe result f16 [49][34]

    // ---- stage V halo (f16, zero-padded at image boundary) ----
    for (int idx = l; idx < HALO * HALO * 8; idx += 64) {
        int p  = idx >> 3;
        int d4 = (idx & 7) * 4;
        int ry = row0 - 1 + p / HALO, rx = col0 - 1 + p % HALO;
        bool in = (ry >= 0 && ry < H && rx >= 0 && rx < W);
        float4 f = make_float4(0.f, 0.f, 0.f, 0.f);
        if (in) f = *reinterpret_cast<const float4*>(vb + ((size_t)ry * W + rx) * C + c0 + d4);
        h2 a  = __builtin_amdgcn_cvt_pkrtz(f.x, f.y);
        h2 b2 = __builtin_amdgcn_cvt_pkrtz(f.z, f.w);
        v4h v4 = { a.x, a.y, b2.x, b2.y };
        *reinterpret_cast<v4h*>(&sVh[p * VHST + d4]) = v4;
    }
    // ---- stage lepe weights as h2-pairs: sW2[cp*20+2t+e] = lw[(c0+2cp+e)*9+t] ----
    for (int i = l; i < 288; i += 64) {
        int d = i / 9, t = i - d * 9;
        sW2[(d >> 1) * 20 + 2 * t + (d & 1)] = (__fp16)lw[(size_t)(c0 + d) * 9 + t];
    }
    __syncthreads();

    const float bias0 = lb[c0 + lr];
    const float bias1 = lb[c0 + 16 + lr];

    // pixel p (clamped to 48) -> global offset of its channel block
    auto pixoff = [&](int p) -> size_t {
        p = p > 48 ? 48 : p;
        int r = row0 + p / WS, c = col0 + p % WS;
        return ((size_t)r * W + c) * C + c0;
    };

    const float scale = 0.17677669529663687f;   // 32^-0.5

    // ---- Q A/B-frags [m][s]: Q[16m+lr][16s+4gq+j], scale folded ----
    v4h qf[4][2];
    #pragma unroll
    for (int m = 0; m < 4; ++m) {
        size_t off = pixoff(16 * m + lr);
        #pragma unroll
        for (int s = 0; s < 2; ++s) {
            float4 f = *reinterpret_cast<const float4*>(qb + off + 16 * s + 4 * gq);
            h2 a  = __builtin_amdgcn_cvt_pkrtz(f.x * scale, f.y * scale);
            h2 b2 = __builtin_amdgcn_cvt_pkrtz(f.z * scale, f.w * scale);
            qf[m][s] = v4h{ a.x, a.y, b2.x, b2.y };
        }
    }
    // ---- K frags [t][s]: K[16t+lr][16s+4gq+j] ----
    v4h kf[4][2];
    #pragma unroll
    for (int t = 0; t < 4; ++t) {
        size_t off = pixoff(16 * t + lr);
        #pragma unroll
        for (int s = 0; s < 2; ++s) {
            float4 f = *reinterpret_cast<const float4*>(kb + off + 16 * s + 4 * gq);
            h2 a  = __builtin_amdgcn_cvt_pkrtz(f.x, f.y);
            h2 b2 = __builtin_amdgcn_cvt_pkrtz(f.z, f.w);
            kf[t][s] = v4h{ a.x, a.y, b2.x, b2.y };
        }
    }

    // ---- V B-frags [s4][n]: V[16s4+4gq+j][16n+lr], read from sVh (f16) ----
    v4h vf[4][2];
    #pragma unroll
    for (int s4 = 0; s4 < 4; ++s4) {
        #pragma unroll
        for (int j = 0; j < 4; ++j) {
            int p  = 16 * s4 + 4 * gq + j;
            int pc = p > 48 ? 48 : p;
            int hp = (pc / WS + 1) * HALO + pc % WS + 1;
            int base = hp * VHST + lr;
            vf[s4][0][j] = sVh[base];
            vf[s4][1][j] = sVh[base + 16];
        }
    }

    // ---- cooperative LePE: sLepe[pix][ch] via packed f16 fma ----
    {
        h2 w2r[9];
        #pragma unroll
        for (int t = 0; t < 9; ++t)
            w2r[t] = *reinterpret_cast<const h2*>(&sW2[lr * 20 + 2 * t]);
        #pragma unroll 1
        for (int it = 0; it < 13; ++it) {
            int pix = it * 4 + gq;               // cp = lr
            if (pix < WIN) {
                int wy = pix / WS, wx = pix - (pix / WS) * WS;
                h2 acc = h2{ (__fp16)0.f, (__fp16)0.f };
                #pragma unroll
                for (int dh = 0; dh < 3; ++dh)
                    #pragma unroll
                    for (int dw = 0; dw < 3; ++dw) {
                        h2 v = *reinterpret_cast<const h2*>(
                            &sVh[((wy + dh) * HALO + (wx + dw)) * VHST + 2 * lr]);
                        acc += w2r[dh * 3 + dw] * v;
                    }
                *reinterpret_cast<h2*>(&sLepe[pix * LST + 2 * lr]) = acc;
            }
        }
    }
    __syncthreads();

    // ---- per query-tile: swapped QK^T (S^T) -> exp -> in-lane normalize -> PV ----
    // No LDS, no barriers in this loop: P is born in the PV A-fragment layout.
    #pragma unroll 1
    for (int mq = 0; mq < 4; ++mq) {
        // sa[tk][r] = S[query=16mq+lr][key=16tk+4gq+r]
        v4f sa[4] = { v4f{0,0,0,0}, v4f{0,0,0,0}, v4f{0,0,0,0}, v4f{0,0,0,0} };
        #pragma unroll
        for (int tk = 0; tk < 4; ++tk)
            #pragma unroll
            for (int s = 0; s < 2; ++s)
                sa[tk] = __builtin_amdgcn_mfma_f32_16x16x16f16(kf[tk][s], qf[mq][s], sa[tk], 0, 0, 0);

        // P~ = exp(score - 3), masked keys -> 0; row-sum across the 4 gq-groups
        float den = 0.f;
        #pragma unroll
        for (int tk = 0; tk < 4; ++tk)
            #pragma unroll
            for (int r = 0; r < 4; ++r) {
                float e = (16 * tk + 4 * gq + r < WIN) ? __expf(sa[tk][r] - 3.f) : 0.f;
                sa[tk][r] = e;
                den += e;
            }
        den += __shfl_xor(den, 16);
        den += __shfl_xor(den, 32);
        const float inv = __builtin_amdgcn_rcpf(den);

        // normalize in-register, pack to f16 A-fragments: pa[s4][j] = P[lr][16s4+4gq+j]
        v4f oa0 = v4f{0,0,0,0}, oa1 = v4f{0,0,0,0};
        #pragma unroll
        for (int s4 = 0; s4 < 4; ++s4) {
            h2 p01 = __builtin_amdgcn_cvt_pkrtz(sa[s4][0] * inv, sa[s4][1] * inv);
            h2 p23 = __builtin_amdgcn_cvt_pkrtz(sa[s4][2] * inv, sa[s4][3] * inv);
            v4h pa = v4h{ p01.x, p01.y, p23.x, p23.y };
            oa0 = __builtin_amdgcn_mfma_f32_16x16x16f16(pa, vf[s4][0], oa0, 0, 0, 0);
            oa1 = __builtin_amdgcn_mfma_f32_16x16x16f16(pa, vf[s4][1], oa1, 0, 0, 0);
        }

        // epilogue: + lepe + bias, store (pixel p = 16mq+4gq+r, ch = 16n+lr)
        #pragma unroll
        for (int r = 0; r < 4; ++r) {
            int p = 16 * mq + 4 * gq + r;
            if (p < WIN) {
                int rr = row0 + p / WS, cc = col0 + p % WS;
                float* dst = out + ((size_t)b * N + (size_t)rr * W + cc) * C + c0 + lr;
                dst[0]  = oa0[r] + (float)sLepe[p * LST + lr]      + bias0;
                dst[16] = oa1[r] + (float)sLepe[p * LST + 16 + lr] + bias1;
            }
        }
    }
}

extern "C" void kernel_launch(void* const* d_in, const int* in_sizes, int n_in,
                              void* d_out, int out_size, void* d_ws, size_t ws_size,
                              hipStream_t stream) {
    const float* qkv = (const float*)d_in[0];
    const float* lw  = (const float*)d_in[1];
    const float* lb  = (const float*)d_in[2];
    float* out = (float*)d_out;

    const int H = 112, W = 112;
    const int C = in_sizes[2];
    const int N = H * W;
    const int B = in_sizes[0] / (3 * N * C);
    const int G = (H / WS) * (W / WS);

    const int units = B * G * NH;   // 16384
    win_attn_lepe<<<units, 64, 0, stream>>>(qkv, lw, lb, out, B, H, W, C);
}

// Round 9
// 126.402 us; speedup vs baseline: 2.0133x; 1.1537x over previous
//
#include <hip/hip_runtime.h>

#define WS   7
#define NH   8
#define HD   32
#define WIN  49
#define HALO 9
#define VHST 36      // sVh row stride in halfs (72B rows, 8B aligned)
#define LST  34      // sLepe row stride in halfs (68B rows, h2-aligned)
#define UPB  4       // independent units (waves) per block

typedef __fp16 h2  __attribute__((ext_vector_type(2)));
typedef __fp16 v4h __attribute__((ext_vector_type(4)));
typedef float  v4f __attribute__((ext_vector_type(4)));

// wave-local LDS fence: this wave's ds_writes are visible to its own ds_reads.
// (waves in a block are fully independent -> no __syncthreads, no coupling)
#define WAVE_LDS_FENCE() asm volatile("s_waitcnt lgkmcnt(0)" ::: "memory")

__device__ __forceinline__ float fexp2(float x) {
    float r;
    asm("v_exp_f32 %0, %1" : "=v"(r) : "v"(x));
    return r;
}

__global__ __launch_bounds__(64 * UPB, 4)
void win_attn_lepe(const float* __restrict__ qkv,
                   const float* __restrict__ lw,
                   const float* __restrict__ lb,
                   float* __restrict__ out,
                   int B, int H, int W, int C)
{
    const int N  = H * W;
    const int Gw = W / WS;
    const int G  = (H / WS) * Gw;

    const int wave = threadIdx.x >> 6;
    const int l    = threadIdx.x & 63;

    const int unit = blockIdx.x * UPB + wave;   // (window)*NH + head
    const int wid  = unit >> 3;
    const int h    = unit & 7;
    const int b    = wid / G;
    const int g    = wid % G;
    const int gy   = g / Gw, gx = g % Gw;
    const int row0 = gy * WS, col0 = gx * WS;
    const int c0   = h * HD;

    const size_t plane = (size_t)B * N * C;
    const float* qb = qkv + (size_t)b * N * C;
    const float* kb = qb + plane;
    const float* vb = qb + 2 * plane;

    const int lr = l & 15;     // A-row / B-col / C-col index
    const int gq = l >> 4;     // k-group

    __shared__ __fp16 sVh  [UPB][HALO * HALO * VHST]; // V halo f16 [81][36]
    __shared__ __fp16 sW2  [UPB][16 * 20];            // lepe w as h2: [cp][2t+e]
    __shared__ __fp16 sLepe[UPB][WIN * LST];          // lepe result f16 [49][34]

    // ---- stage V halo (f16, zero-padded at image boundary) ----
    for (int idx = l; idx < HALO * HALO * 8; idx += 64) {
        int p  = idx >> 3;
        int d4 = (idx & 7) * 4;
        int ry = row0 - 1 + p / HALO, rx = col0 - 1 + p % HALO;
        bool in = (ry >= 0 && ry < H && rx >= 0 && rx < W);
        float4 f = make_float4(0.f, 0.f, 0.f, 0.f);
        if (in) f = *reinterpret_cast<const float4*>(vb + ((size_t)ry * W + rx) * C + c0 + d4);
        h2 a  = __builtin_amdgcn_cvt_pkrtz(f.x, f.y);
        h2 b2 = __builtin_amdgcn_cvt_pkrtz(f.z, f.w);
        v4h v4 = { a.x, a.y, b2.x, b2.y };
        *reinterpret_cast<v4h*>(&sVh[wave][p * VHST + d4]) = v4;
    }
    // ---- stage lepe weights as h2-pairs: sW2[cp*20+2t+e] = lw[(c0+2cp+e)*9+t] ----
    for (int i = l; i < 288; i += 64) {
        int d = i / 9, t = i - d * 9;
        sW2[wave][(d >> 1) * 20 + 2 * t + (d & 1)] = (__fp16)lw[(size_t)(c0 + d) * 9 + t];
    }
    WAVE_LDS_FENCE();

    const float bias0 = lb[c0 + lr];
    const float bias1 = lb[c0 + 16 + lr];

    // pixel p (clamped to 48) -> global offset of its channel block
    auto pixoff = [&](int p) -> size_t {
        p = p > 48 ? 48 : p;
        int r = row0 + p / WS, c = col0 + p % WS;
        return ((size_t)r * W + c) * C + c0;
    };

    // 32^-0.5 * log2(e): exp(x) computed as v_exp_f32(x*log2e)
    const float scale = 0.17677669529663687f * 1.4426950408889634f;
    const float ESHIFT = 4.328085122666891f;   // 3*log2e, normalization-invariant

    // ---- Q frags [m][s]: Q[16m+lr][16s+4gq+j], scale folded ----
    v4h qf[4][2];
    #pragma unroll
    for (int m = 0; m < 4; ++m) {
        size_t off = pixoff(16 * m + lr);
        #pragma unroll
        for (int s = 0; s < 2; ++s) {
            float4 f = *reinterpret_cast<const float4*>(qb + off + 16 * s + 4 * gq);
            h2 a  = __builtin_amdgcn_cvt_pkrtz(f.x * scale, f.y * scale);
            h2 b2 = __builtin_amdgcn_cvt_pkrtz(f.z * scale, f.w * scale);
            qf[m][s] = v4h{ a.x, a.y, b2.x, b2.y };
        }
    }
    // ---- K frags [t][s]: K[16t+lr][16s+4gq+j] ----
    v4h kf[4][2];
    #pragma unroll
    for (int t = 0; t < 4; ++t) {
        size_t off = pixoff(16 * t + lr);
        #pragma unroll
        for (int s = 0; s < 2; ++s) {
            float4 f = *reinterpret_cast<const float4*>(kb + off + 16 * s + 4 * gq);
            h2 a  = __builtin_amdgcn_cvt_pkrtz(f.x, f.y);
            h2 b2 = __builtin_amdgcn_cvt_pkrtz(f.z, f.w);
            kf[t][s] = v4h{ a.x, a.y, b2.x, b2.y };
        }
    }

    // ---- V B-frags [s4][n]: V[16s4+4gq+j][16n+lr], read from sVh (f16) ----
    v4h vf[4][2];
    #pragma unroll
    for (int s4 = 0; s4 < 4; ++s4) {
        #pragma unroll
        for (int j = 0; j < 4; ++j) {
            int p  = 16 * s4 + 4 * gq + j;
            int pc = p > 48 ? 48 : p;
            int hp = (pc / WS + 1) * HALO + pc % WS + 1;
            int base = hp * VHST + lr;
            vf[s4][0][j] = sVh[wave][base];
            vf[s4][1][j] = sVh[wave][base + 16];
        }
    }

    // ---- cooperative LePE: sLepe[pix][ch] via packed f16 fma ----
    {
        h2 w2r[9];
        #pragma unroll
        for (int t = 0; t < 9; ++t)
            w2r[t] = *reinterpret_cast<const h2*>(&sW2[wave][lr * 20 + 2 * t]);
        #pragma unroll 1
        for (int it = 0; it < 13; ++it) {
            int pix = it * 4 + gq;               // cp = lr
            if (pix < WIN) {
                int wy = pix / WS, wx = pix - (pix / WS) * WS;
                h2 acc = h2{ (__fp16)0.f, (__fp16)0.f };
                #pragma unroll
                for (int dh = 0; dh < 3; ++dh)
                    #pragma unroll
                    for (int dw = 0; dw < 3; ++dw) {
                        h2 v = *reinterpret_cast<const h2*>(
                            &sVh[wave][((wy + dh) * HALO + (wx + dw)) * VHST + 2 * lr]);
                        acc += w2r[dh * 3 + dw] * v;
                    }
                *reinterpret_cast<h2*>(&sLepe[wave][pix * LST + 2 * lr]) = acc;
            }
        }
    }
    WAVE_LDS_FENCE();

    // ---- per query-tile: swapped QK^T (S^T) -> exp2 -> in-lane normalize -> PV ----
    // No LDS bounce, no barriers: P is born in the PV A-fragment layout.
    #pragma unroll 1
    for (int mq = 0; mq < 4; ++mq) {
        // sa[tk][r] = S[query=16mq+lr][key=16tk+4gq+r] (pre-scaled by log2e)
        v4f sa[4] = { v4f{0,0,0,0}, v4f{0,0,0,0}, v4f{0,0,0,0}, v4f{0,0,0,0} };
        #pragma unroll
        for (int tk = 0; tk < 4; ++tk)
            #pragma unroll
            for (int s = 0; s < 2; ++s)
                sa[tk] = __builtin_amdgcn_mfma_f32_16x16x16f16(kf[tk][s], qf[mq][s], sa[tk], 0, 0, 0);

        // P~ = 2^(s - 3log2e); keys 0..47 always valid, only (tk=3,gq=0,r=0)=key48 valid in tail
        float den = 0.f;
        #pragma unroll
        for (int tk = 0; tk < 3; ++tk)
            #pragma unroll
            for (int r = 0; r < 4; ++r) {
                float e = fexp2(sa[tk][r] - ESHIFT);
                sa[tk][r] = e;
                den += e;
            }
        {
            float e0 = (gq == 0) ? fexp2(sa[3][0] - ESHIFT) : 0.f;
            sa[3][0] = e0; sa[3][1] = 0.f; sa[3][2] = 0.f; sa[3][3] = 0.f;
            den += e0;
        }
        den += __shfl_xor(den, 16);
        den += __shfl_xor(den, 32);
        const float inv = __builtin_amdgcn_rcpf(den);

        // normalize in-register, pack to f16 A-fragments: pa[s4][j] = P[lr][16s4+4gq+j]
        v4f oa0 = v4f{0,0,0,0}, oa1 = v4f{0,0,0,0};
        #pragma unroll
        for (int s4 = 0; s4 < 4; ++s4) {
            h2 p01 = __builtin_amdgcn_cvt_pkrtz(sa[s4][0] * inv, sa[s4][1] * inv);
            h2 p23 = __builtin_amdgcn_cvt_pkrtz(sa[s4][2] * inv, sa[s4][3] * inv);
            v4h pa = v4h{ p01.x, p01.y, p23.x, p23.y };
            oa0 = __builtin_amdgcn_mfma_f32_16x16x16f16(pa, vf[s4][0], oa0, 0, 0, 0);
            oa1 = __builtin_amdgcn_mfma_f32_16x16x16f16(pa, vf[s4][1], oa1, 0, 0, 0);
        }

        // epilogue: + lepe + bias, store (pixel p = 16mq+4gq+r, ch = 16n+lr)
        #pragma unroll
        for (int r = 0; r < 4; ++r) {
            int p = 16 * mq + 4 * gq + r;
            if (p < WIN) {
                int rr = row0 + p / WS, cc = col0 + p % WS;
                float* dst = out + ((size_t)b * N + (size_t)rr * W + cc) * C + c0 + lr;
                dst[0]  = oa0[r] + (float)sLepe[wave][p * LST + lr]      + bias0;
                dst[16] = oa1[r] + (float)sLepe[wave][p * LST + 16 + lr] + bias1;
            }
        }
    }
}

extern "C" void kernel_launch(void* const* d_in, const int* in_sizes, int n_in,
                              void* d_out, int out_size, void* d_ws, size_t ws_size,
                              hipStream_t stream) {
    const float* qkv = (const float*)d_in[0];
    const float* lw  = (const float*)d_in[1];
    const float* lb  = (const float*)d_in[2];
    float* out = (float*)d_out;

    const int H = 112, W = 112;
    const int C = in_sizes[2];
    const int N = H * W;
    const int B = in_sizes[0] / (3 * N * C);
    const int G = (H / WS) * (W / WS);

    const int units = B * G * NH;   // 16384, divisible by UPB
    win_attn_lepe<<<units / UPB, 64 * UPB, 0, stream>>>(qkv, lw, lb, out, B, H, W, C);
}